// Round 12
// baseline (231.652 us; speedup 1.0000x reference)
//
#include <hip/hip_runtime.h>
#include <hip/hip_bf16.h>

typedef __bf16 bf16x8 __attribute__((ext_vector_type(8)));
typedef __bf16 bf16x4 __attribute__((ext_vector_type(4)));
typedef float f32x4 __attribute__((ext_vector_type(4)));

#define B_ 2
#define S_ 2048
#define D_ 1024
#define H_ 16
#define HD_ 64
#define NT_ (S_ / 64)   // 32 k-tiles in attn

__device__ inline void load_lds16(const __bf16* g, __bf16* l) {
  __builtin_amdgcn_global_load_lds(
      (const __attribute__((address_space(1))) void*)g,
      (__attribute__((address_space(3))) void*)l, 16, 0, 0);
}

// ---------------------------------------------------------------------------
// prep: z<3  -> transpose+convert W_z (fp32 [k][n]) to bf16 WT[z][n][k]
//       z==3 -> convert X fp32 -> bf16 (same layout)
// ---------------------------------------------------------------------------
__global__ __launch_bounds__(256) void prep(
    const float* __restrict__ X,
    const float* __restrict__ Wq, const float* __restrict__ Wk,
    const float* __restrict__ Wv,
    __bf16* __restrict__ Xb, __bf16* __restrict__ WT)
{
  const int z = blockIdx.z, t = threadIdx.x;
  if (z == 3) {
    size_t base = ((size_t)(blockIdx.y * 16 + blockIdx.x)) * 16384 + t * 4;
#pragma unroll
    for (int i = 0; i < 16; ++i) {
      size_t idx = base + (size_t)i * 1024;
      f32x4 v = *(const f32x4*)(X + idx);
      __bf16 o[4];
#pragma unroll
      for (int j = 0; j < 4; ++j) o[j] = (__bf16)v[j];
      *(ulong1*)(Xb + idx) = *(ulong1*)o;
    }
    return;
  }
  const float* W = (z == 0) ? Wq : (z == 1) ? Wk : Wv;
  __bf16* WTz = WT + (size_t)z * D_ * D_;
  const int k0 = blockIdx.y * 64, n0 = blockIdx.x * 64;

  __shared__ __bf16 T[64 * 72];
  {
    int kl = t >> 2, cg = (t & 3) * 16;
    const float* wp = W + (size_t)(k0 + kl) * D_ + n0 + cg;
    bf16x8 a, b;
#pragma unroll
    for (int j = 0; j < 4; ++j) { a[j] = (__bf16)wp[j];     a[4 + j] = (__bf16)wp[4 + j]; }
#pragma unroll
    for (int j = 0; j < 4; ++j) { b[j] = (__bf16)wp[8 + j]; b[4 + j] = (__bf16)wp[12 + j]; }
    *(bf16x8*)(T + kl * 72 + cg) = a;
    *(bf16x8*)(T + kl * 72 + cg + 8) = b;
  }
  __syncthreads();
  {
    int nl = t >> 2, kc = (t & 3) * 16;
    bf16x8 a, b;
#pragma unroll
    for (int j = 0; j < 8; ++j) a[j] = T[(kc + j) * 72 + nl];
#pragma unroll
    for (int j = 0; j < 8; ++j) b[j] = T[(kc + 8 + j) * 72 + nl];
    __bf16* op = WTz + (size_t)(n0 + nl) * D_ + k0 + kc;
    *(bf16x8*)(op) = a;
    *(bf16x8*)(op + 8) = b;
  }
}

// ---------------------------------------------------------------------------
// QKV projection (m97 structure + XOR-swizzled LDS, unchanged from R8)
// ---------------------------------------------------------------------------
__global__ __launch_bounds__(256) void qkv_gemm(
    const __bf16* __restrict__ Xb, const __bf16* __restrict__ WT,
    const float* __restrict__ bq, const float* __restrict__ bk,
    const float* __restrict__ bv,
    __bf16* __restrict__ Qw, __bf16* __restrict__ Kw, __bf16* __restrict__ VTw)
{
  const int z = blockIdx.z;
  const __bf16* Wz = WT + (size_t)z * D_ * D_;
  const float* bias = (z == 0) ? bq : (z == 1) ? bk : bv;
  __bf16* outp = (z == 0) ? Qw : (z == 1) ? Kw : VTw;
  const float mult = (z == 0) ? 0.125f * 1.44269504088896f : 1.0f;

  const int tid  = threadIdx.x;
  const int wave = tid >> 6, lane = tid & 63, ln = lane & 15, quad = lane >> 4;
  const int m0 = blockIdx.y * 128, n0 = blockIdx.x * 128;
  const int wm = (wave & 1) * 64, wn = (wave >> 1) * 64;

  __shared__ __bf16 Als[128 * 32];
  __shared__ __bf16 Bls[128 * 32];

  f32x4 acc[4][4] = {};

  for (int k0 = 0; k0 < D_; k0 += 32) {
    __syncthreads();
#pragma unroll
    for (int i = 0; i < 2; ++i) {
      int cb = wave * 128 + i * 64;
      int chunk = cb + lane;
      int row = chunk >> 2, c = chunk & 3;
      int gc = c ^ (row & 3);
      load_lds16(Xb + (size_t)(m0 + row) * D_ + k0 + gc * 8, Als + cb * 8);
      load_lds16(Wz + (size_t)(n0 + row) * D_ + k0 + gc * 8, Bls + cb * 8);
    }
    __syncthreads();

    bf16x8 af[4], bfr[4];
    const int dsw = (quad ^ (ln & 3)) * 8;
#pragma unroll
    for (int mt = 0; mt < 4; ++mt)
      af[mt] = *(const bf16x8*)(Als + (wm + mt * 16 + ln) * 32 + dsw);
#pragma unroll
    for (int nt = 0; nt < 4; ++nt)
      bfr[nt] = *(const bf16x8*)(Bls + (wn + nt * 16 + ln) * 32 + dsw);
#pragma unroll
    for (int mt = 0; mt < 4; ++mt)
#pragma unroll
      for (int nt = 0; nt < 4; ++nt)
        acc[mt][nt] = __builtin_amdgcn_mfma_f32_16x16x32_bf16(af[mt], bfr[nt], acc[mt][nt], 0, 0, 0);
  }

#pragma unroll
  for (int nt = 0; nt < 4; ++nt) {
    int n_g = n0 + wn + nt * 16 + ln;
    float bv_ = bias[n_g];
#pragma unroll
    for (int mt = 0; mt < 4; ++mt) {
      if (z < 2) {
#pragma unroll
        for (int r = 0; r < 4; ++r) {
          int m_g = m0 + wm + mt * 16 + quad * 4 + r;
          outp[(size_t)m_g * D_ + n_g] = (__bf16)((acc[mt][nt][r] + bv_) * mult);
        }
      } else {
        int m_g0 = m0 + wm + mt * 16 + quad * 4;
        bf16x4 v4;
#pragma unroll
        for (int r = 0; r < 4; ++r) v4[r] = (__bf16)(acc[mt][nt][r] + bv_);
        *(bf16x4*)(outp + (size_t)(m_g0 >> 11) * D_ * S_ + (size_t)n_g * S_ + (m_g0 & (S_ - 1))) = v4;
      }
    }
  }
}

// ---------------------------------------------------------------------------
// Flash attention v8 (barrier-free): 4 waves/WG (256 thr), 32 q/wave, grid
// 512 (same wave budget as R8). K-frags and V-frags read DIRECTLY from
// global (8 KB tiles stay hot in the 32 KB per-CU L1; 16 WGs per bh pinned
// to one XCD keep them hot in L2). K-frags double-buffered in registers one
// tile ahead; V-frags issued at tile top, consumed after QK+exp. Only P's
// C->A transpose goes through (per-wave, XOR-swizzled) LDS -> same-wave DS
// ordering, ZERO __syncthreads in the kernel. Row sums: per-lane VALU adds,
// quad-reduce by 2 shuffles at the end. Unnormalized exp2 softmax.
// ---------------------------------------------------------------------------
__global__ __launch_bounds__(256) void attn(
    const __bf16* __restrict__ Q, const __bf16* __restrict__ K,
    const __bf16* __restrict__ VT, float* __restrict__ out)
{
  const int tid  = threadIdx.x;
  const int wave = tid >> 6, lane = tid & 63, ln = lane & 15, quad = lane >> 4;

  const int f = blockIdx.x;
  const int xcd = f & 7, g = f >> 3;
  const int bh = ((g & 3) << 3) | xcd;   // 16 WGs per bh, one XCD
  const int qt = g >> 2;                 // 0..15 (128-row q tiles)
  const int b = bh >> 4, h = bh & 15;
  const int q0 = qt * 128 + wave * 32;   // 32 q rows per wave

  // Q B-frags (regs whole kernel): lane n=ln -> q row, k = ks*32+quad*8+j
  const __bf16* Qbase = Q + (size_t)(b * S_ + q0) * D_ + h * HD_;
  bf16x8 qb[2][2];
#pragma unroll
  for (int nt = 0; nt < 2; ++nt)
#pragma unroll
    for (int ks = 0; ks < 2; ++ks)
      qb[nt][ks] = *(const bf16x8*)(Qbase + (size_t)(nt * 16 + ln) * D_ + ks * 32 + quad * 8);

  const __bf16* Kh = K + (size_t)b * S_ * D_ + h * HD_;        // [key][d]
  const __bf16* Vh = VT + (size_t)(b * D_ + h * HD_) * S_;     // [d][s]

  // per-wave P buffer only; XOR-swizzled stride-64 rows
  __shared__ __bf16 Pls[4][32 * 64];   // 16 KB
  __shared__ float  Linv[4][32];
  __bf16* Pw = Pls[wave];

  f32x4 acc[2][4] = {};                // [q-mt][d-tile]
  float lsum[2] = {0.f, 0.f};          // per-lane partial row sums (q = nt*16+ln)
  const int swl = ln & 7;

  // K-frag base: row mt*16+ln, 32B half ks -> advance 64*D_ per tile
  const __bf16* Kf = Kh + (size_t)ln * D_ + quad * 8;
  // V-frag base: row dt*16+ln, col window kt*64 + ks*32 + quad*8
  const __bf16* Vf = Vh + (size_t)ln * S_ + quad * 8;

  bf16x8 kaA[8], kaB[8];               // [mt*2+ks] double buffer
#pragma unroll
  for (int i = 0; i < 8; ++i) {
    int mt = i >> 1, ks = i & 1;
    kaA[i] = *(const bf16x8*)(Kf + (size_t)(mt * 16) * D_ + ks * 32);
  }

  auto tile = [&](int kt, bf16x8 (&kc)[8], bf16x8 (&kn)[8]) {
    // V-frags for this tile (consumed after QK+exp; latency covered)
    bf16x8 vb[8];
#pragma unroll
    for (int i = 0; i < 8; ++i) {
      int ks = i >> 2, dt = i & 3;
      vb[i] = *(const bf16x8*)(Vf + (size_t)(dt * 16) * S_ + kt * 64 + ks * 32);
    }
    // prefetch next tile's K-frags
    if (kt + 1 < NT_) {
#pragma unroll
      for (int i = 0; i < 8; ++i) {
        int mt = i >> 1, ks = i & 1;
        kn[i] = *(const bf16x8*)(Kf + (size_t)((kt + 1) * 64 + mt * 16) * D_ + ks * 32);
      }
    }

    // S^T = K * Q^T  (C: row=key(quad*4+r), col=q(ln))
    f32x4 st[4][2] = {};
#pragma unroll
    for (int mt = 0; mt < 4; ++mt)
#pragma unroll
      for (int ks = 0; ks < 2; ++ks)
#pragma unroll
        for (int nt = 0; nt < 2; ++nt)
          st[mt][nt] = __builtin_amdgcn_mfma_f32_16x16x32_bf16(kc[mt * 2 + ks], qb[nt][ks], st[mt][nt], 0, 0, 0);

    // exp2; per-lane row-sum partials; pack 4 keys -> swizzled ds_write_b64
#pragma unroll
    for (int mt = 0; mt < 4; ++mt)
#pragma unroll
      for (int nt = 0; nt < 2; ++nt) {
        bf16x4 pk;
#pragma unroll
        for (int r = 0; r < 4; ++r) {
          float p = __builtin_amdgcn_exp2f(st[mt][nt][r]);
          lsum[nt] += p;
          pk[r] = (__bf16)p;
        }
        *(bf16x4*)(Pw + (nt * 16 + ln) * 64 + ((2 * mt + (quad >> 1)) ^ swl) * 8 + (quad & 1) * 4) = pk;
      }

    // O += P * V ; P A-frags same-wave LDS round-trip (in-order DS pipe)
#pragma unroll
    for (int ks = 0; ks < 2; ++ks) {
      bf16x8 pa[2];
#pragma unroll
      for (int mt = 0; mt < 2; ++mt)
        pa[mt] = *(const bf16x8*)(Pw + (mt * 16 + ln) * 64 + ((ks * 4 + quad) ^ swl) * 8);
#pragma unroll
      for (int dt = 0; dt < 4; ++dt)
#pragma unroll
        for (int mt = 0; mt < 2; ++mt)
          acc[mt][dt] = __builtin_amdgcn_mfma_f32_16x16x32_bf16(pa[mt], vb[ks * 4 + dt], acc[mt][dt], 0, 0, 0);
    }
  };

  for (int kt = 0; kt < NT_; kt += 2) {
    tile(kt, kaA, kaB);
    tile(kt + 1, kaB, kaA);
  }

  // full row sums: reduce across the 4 quads (keys were split across quads)
#pragma unroll
  for (int nt = 0; nt < 2; ++nt) {
    lsum[nt] += __shfl_xor(lsum[nt], 16);
    lsum[nt] += __shfl_xor(lsum[nt], 32);
  }
  if (quad == 0) {
    Linv[wave][ln]      = 1.0f / lsum[0];
    Linv[wave][16 + ln] = 1.0f / lsum[1];
  }
  // same-wave LDS write->read; no barrier needed

  // store out[b][q][h*64+d] (fp32), rows q = q0 + mt*16 + quad*4 + r
#pragma unroll
  for (int mt = 0; mt < 2; ++mt)
#pragma unroll
    for (int r = 0; r < 4; ++r) {
      float li = Linv[wave][mt * 16 + quad * 4 + r];
      float* op = out + (size_t)(b * S_ + q0 + mt * 16 + quad * 4 + r) * D_ + h * HD_;
#pragma unroll
      for (int dt = 0; dt < 4; ++dt)
        op[dt * 16 + ln] = acc[mt][dt][r] * li;
    }
}

extern "C" void kernel_launch(void* const* d_in, const int* in_sizes, int n_in,
                              void* d_out, int out_size, void* d_ws, size_t ws_size,
                              hipStream_t stream) {
  const float* X  = (const float*)d_in[0];
  const float* Wq = (const float*)d_in[1];
  const float* bq = (const float*)d_in[2];
  const float* Wk = (const float*)d_in[3];
  const float* bk = (const float*)d_in[4];
  const float* Wv = (const float*)d_in[5];
  const float* bv = (const float*)d_in[6];

  __bf16* Qw  = (__bf16*)d_ws;                        // 8 MB
  __bf16* Kw  = Qw  + (size_t)B_ * S_ * D_;           // 8 MB
  __bf16* VTw = Kw  + (size_t)B_ * S_ * D_;           // 8 MB
  __bf16* Xb  = VTw + (size_t)B_ * S_ * D_;           // 8 MB
  __bf16* WT  = Xb  + (size_t)B_ * S_ * D_;           // 6 MB
  float* out = (float*)d_out;

  prep<<<dim3(16, 16, 4), 256, 0, stream>>>(X, Wq, Wk, Wv, Xb, WT);
  qkv_gemm<<<dim3(8, 32, 3), 256, 0, stream>>>(Xb, WT, bq, bk, bv, Qw, Kw, VTw);
  attn<<<512, 256, 0, stream>>>(Qw, Kw, VTw, out);
}